// Round 4
// baseline (556.468 us; speedup 1.0000x reference)
//
#include <hip/hip_runtime.h>
#include <hip/hip_bf16.h>
#include <math.h>

#define Bb 32
#define Hh 56
#define Ww 56
#define Cc 128
#define HEAD 4
#define WS 7
#define SHIFT 3
#define Nn 49
#define NWw 64
#define HD 32
#define HID 512
#define TOK (Bb*Hh*Ww)
#define SCALEF 0.17677669529663687f

typedef short short8 __attribute__((ext_vector_type(8)));
typedef float f32x4 __attribute__((ext_vector_type(4)));

__device__ __forceinline__ short f2bf(float f) {
    union { float f; unsigned u; } c; c.f = f;
    unsigned r = (c.u + 0x7fff + ((c.u >> 16) & 1)) >> 16;
    return (short)r;
}
__device__ __forceinline__ unsigned pack2bf(float a, float b) {
    return (unsigned)(unsigned short)f2bf(a) | ((unsigned)(unsigned short)f2bf(b) << 16);
}
__device__ __forceinline__ float gelu_fast(float x) {
    float x3 = x * x * x;
    float y = 0.7978845608f * (x + 0.044715f * x3);
    float e = __expf(2.f * y);
    float t = 1.f - 2.f / (e + 1.f);
    return 0.5f * x * (1.f + t);
}
#define LDS_FENCE() asm volatile("s_waitcnt lgkmcnt(0)" ::: "memory")

// ---------------------------------------------------------------------------
// Weight convert + transpose: fp32 [K x N] -> bf16 [N x K]
// ---------------------------------------------------------------------------
__global__ void conv_t(const float* __restrict__ in, short* __restrict__ out,
                       int K, int N) {
    int idx = blockIdx.x * 256 + threadIdx.x;
    if (idx >= K * N) return;
    int k = idx / N, n = idx % N;
    out[(size_t)n * K + k] = f2bf(in[idx]);
}

// ---------------------------------------------------------------------------
// Bias+mask table: [cls(4)][head(4)][row(64)][col(64)] fp32.
// Pad entries (row>=49 or col>=49) = -1e30 (doubles as the col mask).
// ---------------------------------------------------------------------------
__global__ void build_table(const float* __restrict__ rpb, float* __restrict__ table) {
    int idx = blockIdx.x * 256 + threadIdx.x;
    if (idx >= 16 * 4096) return;
    int cell = idx & 4095, ch = idx >> 12;
    int cls = ch >> 2, hd = ch & 3;
    int row = cell >> 6, col = cell & 63;
    float v;
    if (row >= Nn || col >= Nn) v = -1e30f;
    else {
        int i1 = row / 7, j1 = row % 7, i2 = col / 7, j2 = col % 7;
        float bias = rpb[((i1 - i2 + 6) * 13 + (j1 - j2 + 6)) * HEAD + hd];
        int bh = cls >> 1, bw = cls & 1;
        int rn = bh ? (i1 < 4 ? 1 : 2) : 0;
        int cn = bw ? (j1 < 4 ? 1 : 2) : 0;
        int rm = bh ? (i2 < 4 ? 1 : 2) : 0;
        int cm = bw ? (j2 < 4 ? 1 : 2) : 0;
        v = bias + (((rn * 3 + cn) != (rm * 3 + cm)) ? -100.f : 0.f);
    }
    table[idx] = v;
}

// ---------------------------------------------------------------------------
// LN1 + cyclic shift + window partition gather -> bf16 h. 4 rows/block.
// ---------------------------------------------------------------------------
__global__ __launch_bounds__(256) void ln1_gather(const float* __restrict__ x,
                                                  const float* __restrict__ g,
                                                  const float* __restrict__ b,
                                                  short* __restrict__ h) {
    int wave = threadIdx.x >> 6, lane = threadIdx.x & 63;
    int t = blockIdx.x * 4 + wave;
    int bimg = t / (NWw * Nn);
    int wrow = t % (NWw * Nn);
    int wi = wrow / Nn, n = wrow % Nn;
    int wh = wi >> 3, ww = wi & 7;
    int i = n / 7, j = n % 7;
    int sr = (wh * 7 + i + SHIFT) % Hh;
    int scol = (ww * 7 + j + SHIFT) % Ww;
    const float* xr = x + ((size_t)bimg * (Hh * Ww) + sr * Ww + scol) * Cc;
    float2 v = ((const float2*)xr)[lane];
    float s = v.x + v.y;
    #pragma unroll
    for (int m = 32; m; m >>= 1) s += __shfl_xor(s, m, 64);
    float mean = s * (1.f / 128.f);
    float dx = v.x - mean, dy = v.y - mean;
    float vs = dx * dx + dy * dy;
    #pragma unroll
    for (int m = 32; m; m >>= 1) vs += __shfl_xor(vs, m, 64);
    float inv = rsqrtf(vs * (1.f / 128.f) + 1e-5f);
    float2 gg = ((const float2*)g)[lane];
    float2 bb = ((const float2*)b)[lane];
    ((unsigned*)(h + (size_t)t * Cc))[lane] =
        pack2bf(dx * inv * gg.x + bb.x, dy * inv * gg.y + bb.y);
}

// ---------------------------------------------------------------------------
// QKV GEMM, 16 rows/wave, 64 rows/block, 1568 blocks. Q pre-scaled.
// ---------------------------------------------------------------------------
__global__ __launch_bounds__(256) void qkv_mfma(const short* __restrict__ h,
                                                const short* __restrict__ wt,
                                                const float* __restrict__ bias,
                                                short* __restrict__ qkv) {
    int wave = threadIdx.x >> 6, lane = threadIdx.x & 63;
    int row16 = lane & 15, quad = lane >> 4;
    size_t r0 = (size_t)blockIdx.x * 64 + wave * 16;
    short8 afr[4];
    #pragma unroll
    for (int k = 0; k < 4; ++k)
        afr[k] = *(const short8*)(h + (r0 + row16) * Cc + k * 32 + quad * 8);
    for (int ch = 0; ch < 3; ++ch) {
        f32x4 acc[8];
        #pragma unroll
        for (int n = 0; n < 8; ++n) acc[n] = (f32x4)(0.f);
        #pragma unroll
        for (int k = 0; k < 4; ++k) {
            #pragma unroll
            for (int n = 0; n < 8; ++n) {
                short8 bfr = *(const short8*)(wt + (size_t)(ch * 128 + n * 16 + row16) * Cc + k * 32 + quad * 8);
                acc[n] = __builtin_amdgcn_mfma_f32_16x16x32_bf16(afr[k], bfr, acc[n], 0, 0, 0);
            }
        }
        #pragma unroll
        for (int n = 0; n < 8; ++n) {
            int col = ch * 128 + n * 16 + row16;
            float bv = bias[col];
            #pragma unroll
            for (int r = 0; r < 4; ++r) {
                float val = acc[n][r] + bv;
                if (ch == 0) val *= SCALEF;
                qkv[(r0 + quad * 4 + r) * 384 + col] = f2bf(val);
            }
        }
    }
}

// ---------------------------------------------------------------------------
// MFMA attention: one wave per (window, head), unchanged from round 3.
// ---------------------------------------------------------------------------
__global__ __launch_bounds__(256) void attn_mfma(const short* __restrict__ qkv,
                                                 const float* __restrict__ table,
                                                 short* __restrict__ o) {
    __shared__ short Pbuf[4][64 * 72];
    __shared__ short Vbuf[4][32 * 72];
    int wave = threadIdx.x >> 6, lane = threadIdx.x & 63;
    int row16 = lane & 15, quad = lane >> 4;
    int unit = blockIdx.x * 4 + wave;
    int bw = unit >> 2, hd = unit & 3;
    int widx = bw & 63, wh = widx >> 3, ww = widx & 7;
    int cls = ((wh == 7) ? 2 : 0) | ((ww == 7) ? 1 : 0);
    const float* tb = table + ((size_t)(cls * 4 + hd)) * 4096;
    short* P = &Pbuf[wave][0];
    short* vt = &Vbuf[wave][0];
    const short* base = qkv + (size_t)bw * Nn * 384 + hd * HD;

    {
        int t = lane;
        if (t < Nn) {
            const short* vrow = base + (size_t)t * 384 + 256;
            #pragma unroll
            for (int d = 0; d < HD; d += 2) {
                unsigned pr = *(const unsigned*)(vrow + d);
                vt[d * 72 + t] = (short)(pr & 0xffff);
                vt[(d + 1) * 72 + t] = (short)(pr >> 16);
            }
        } else {
            #pragma unroll
            for (int d = 0; d < HD; ++d) vt[d * 72 + t] = 0;
        }
    }

    short8 qa[4], kb[4];
    #pragma unroll
    for (int mt = 0; mt < 4; ++mt) {
        int r = mt * 16 + row16;
        if (r < Nn) {
            qa[mt] = *(const short8*)(base + (size_t)r * 384 + quad * 8);
            kb[mt] = *(const short8*)(base + (size_t)r * 384 + 128 + quad * 8);
        } else {
            qa[mt] = (short8)(short)0;
            kb[mt] = (short8)(short)0;
        }
    }
    f32x4 s[4][4];
    #pragma unroll
    for (int mt = 0; mt < 4; ++mt)
        #pragma unroll
        for (int nt = 0; nt < 4; ++nt)
            s[mt][nt] = __builtin_amdgcn_mfma_f32_16x16x32_bf16(qa[mt], kb[nt], (f32x4)(0.f), 0, 0, 0);

    #pragma unroll
    for (int mt = 0; mt < 4; ++mt) {
        #pragma unroll
        for (int r = 0; r < 4; ++r) {
            int row = mt * 16 + quad * 4 + r;
            float mx = -1e30f;
            #pragma unroll
            for (int nt = 0; nt < 4; ++nt) {
                s[mt][nt][r] += tb[row * 64 + nt * 16 + row16];
                mx = fmaxf(mx, s[mt][nt][r]);
            }
            #pragma unroll
            for (int m = 1; m < 16; m <<= 1) mx = fmaxf(mx, __shfl_xor(mx, m, 64));
            float sm = 0.f;
            #pragma unroll
            for (int nt = 0; nt < 4; ++nt) {
                float e = __expf(s[mt][nt][r] - mx);
                s[mt][nt][r] = e;
                sm += e;
            }
            #pragma unroll
            for (int m = 1; m < 16; m <<= 1) sm += __shfl_xor(sm, m, 64);
            float inv = 1.f / sm;
            #pragma unroll
            for (int nt = 0; nt < 4; ++nt)
                P[row * 72 + nt * 16 + row16] = f2bf(s[mt][nt][r] * inv);
        }
    }
    LDS_FENCE();

    f32x4 oacc[4][2];
    #pragma unroll
    for (int mt = 0; mt < 4; ++mt)
        #pragma unroll
        for (int nt = 0; nt < 2; ++nt) oacc[mt][nt] = (f32x4)(0.f);
    #pragma unroll
    for (int kt = 0; kt < 2; ++kt) {
        short8 pa[4], vb[2];
        #pragma unroll
        for (int mt = 0; mt < 4; ++mt)
            pa[mt] = *(const short8*)(P + (mt * 16 + row16) * 72 + kt * 32 + quad * 8);
        #pragma unroll
        for (int nt = 0; nt < 2; ++nt)
            vb[nt] = *(const short8*)(vt + (nt * 16 + row16) * 72 + kt * 32 + quad * 8);
        #pragma unroll
        for (int mt = 0; mt < 4; ++mt)
            #pragma unroll
            for (int nt = 0; nt < 2; ++nt)
                oacc[mt][nt] = __builtin_amdgcn_mfma_f32_16x16x32_bf16(pa[mt], vb[nt], oacc[mt][nt], 0, 0, 0);
    }
    #pragma unroll
    for (int mt = 0; mt < 4; ++mt)
        #pragma unroll
        for (int nt = 0; nt < 2; ++nt)
            #pragma unroll
            for (int r = 0; r < 4; ++r) {
                int row = mt * 16 + quad * 4 + r;
                if (row < Nn)
                    o[((size_t)bw * Nn + row) * Cc + hd * HD + nt * 16 + row16] = f2bf(oacc[mt][nt][r]);
            }
}

// ---------------------------------------------------------------------------
// Proj GEMM (16 rows/wave) + merge/reverse-shift scatter + residual + LN2.
// ---------------------------------------------------------------------------
__global__ __launch_bounds__(256) void proj_ln2(const short* __restrict__ o,
                                                const short* __restrict__ wt,
                                                const float* __restrict__ pb,
                                                const float* __restrict__ x,
                                                const float* __restrict__ g2,
                                                const float* __restrict__ b2,
                                                float* __restrict__ x1,
                                                short* __restrict__ m) {
    __shared__ int dest[64];
    int tid = threadIdx.x;
    int wave = tid >> 6, lane = tid & 63;
    int row16 = lane & 15, quad = lane >> 4;
    int s0 = blockIdx.x * 64;
    if (tid < 64) {
        int st = s0 + tid;
        int bimg = st / (NWw * Nn);
        int rem = st % (NWw * Nn);
        int wi = rem / Nn, n = rem % Nn;
        int wh = wi >> 3, ww = wi & 7;
        int i = n / 7, j = n % 7;
        int dr = (wh * 7 + i + SHIFT) % Hh;
        int dc = (ww * 7 + j + SHIFT) % Ww;
        dest[tid] = bimg * (Hh * Ww) + dr * Ww + dc;
    }
    __syncthreads();
    int r0w = wave * 16;
    short8 afr[4];
    #pragma unroll
    for (int k = 0; k < 4; ++k)
        afr[k] = *(const short8*)(o + ((size_t)s0 + r0w + row16) * Cc + k * 32 + quad * 8);
    f32x4 acc[8];
    #pragma unroll
    for (int n = 0; n < 8; ++n) acc[n] = (f32x4)(0.f);
    #pragma unroll
    for (int k = 0; k < 4; ++k) {
        #pragma unroll
        for (int n = 0; n < 8; ++n) {
            short8 bfr = *(const short8*)(wt + (size_t)(n * 16 + row16) * Cc + k * 32 + quad * 8);
            acc[n] = __builtin_amdgcn_mfma_f32_16x16x32_bf16(afr[k], bfr, acc[n], 0, 0, 0);
        }
    }
    float gv[8], bv[8], pbv[8];
    #pragma unroll
    for (int n = 0; n < 8; ++n) {
        int col = n * 16 + row16;
        gv[n] = g2[col]; bv[n] = b2[col]; pbv[n] = pb[col];
    }
    #pragma unroll
    for (int r = 0; r < 4; ++r) {
        int di = dest[r0w + quad * 4 + r];
        #pragma unroll
        for (int n = 0; n < 8; ++n)
            acc[n][r] += x[(size_t)di * Cc + n * 16 + row16] + pbv[n];
    }
    #pragma unroll
    for (int r = 0; r < 4; ++r) {
        float sum = 0.f;
        #pragma unroll
        for (int n = 0; n < 8; ++n) sum += acc[n][r];
        #pragma unroll
        for (int mk = 1; mk < 16; mk <<= 1) sum += __shfl_xor(sum, mk, 64);
        float mean = sum * (1.f / 128.f);
        float var = 0.f;
        #pragma unroll
        for (int n = 0; n < 8; ++n) {
            float d = acc[n][r] - mean;
            var += d * d;
        }
        #pragma unroll
        for (int mk = 1; mk < 16; mk <<= 1) var += __shfl_xor(var, mk, 64);
        float inv = rsqrtf(var * (1.f / 128.f) + 1e-5f);
        int di = dest[r0w + quad * 4 + r];
        #pragma unroll
        for (int n = 0; n < 8; ++n) {
            size_t idx = (size_t)di * Cc + n * 16 + row16;
            float v = acc[n][r];
            x1[idx] = v;
            m[idx] = f2bf((v - mean) * inv * gv[n] + bv[n]);
        }
    }
}

// ---------------------------------------------------------------------------
// Fused MLP, 16 tokens/wave, FC1 reoriented (M=hid, N=token) so the LDS
// C->A round-trip is vectorized: 8x ds_write_b64 + 4x ds_read_b128 per chunk.
// ---------------------------------------------------------------------------
#define MSTRIDE 136   // shorts; 272 B = 17*16 keeps b128 reads 16B-aligned
__global__ __launch_bounds__(256) void mlp_mfma(const short* __restrict__ m,
                                                const short* __restrict__ w1t,
                                                const float* __restrict__ b1,
                                                const short* __restrict__ w2t,
                                                const float* __restrict__ b2,
                                                const float* __restrict__ x1,
                                                float* __restrict__ out) {
    __shared__ short Hs[4][16 * MSTRIDE];
    int wave = threadIdx.x >> 6, lane = threadIdx.x & 63;
    int row16 = lane & 15, quad = lane >> 4;
    size_t t0 = (size_t)blockIdx.x * 64 + wave * 16;
    short* Ht = &Hs[wave][0];
    // B fragments: the wave's 16 token rows (reused all chunks)
    short8 bfr[4];
    #pragma unroll
    for (int k = 0; k < 4; ++k)
        bfr[k] = *(const short8*)(m + (t0 + row16) * Cc + k * 32 + quad * 8);
    f32x4 acc2[8];
    #pragma unroll
    for (int n = 0; n < 8; ++n) acc2[n] = (f32x4)(0.f);
    for (int ch = 0; ch < 4; ++ch) {
        // FC1: H^T chunk = w1t rows (A) x tokens (B); C row=hid, col=token
        f32x4 acc1[8];
        #pragma unroll
        for (int mt = 0; mt < 8; ++mt) acc1[mt] = (f32x4)(0.f);
        #pragma unroll
        for (int k = 0; k < 4; ++k) {
            #pragma unroll
            for (int mt = 0; mt < 8; ++mt) {
                short8 a = *(const short8*)(w1t + (size_t)(ch * 128 + mt * 16 + row16) * Cc + k * 32 + quad * 8);
                acc1[mt] = __builtin_amdgcn_mfma_f32_16x16x32_bf16(a, bfr[k], acc1[mt], 0, 0, 0);
            }
        }
        // GELU + packed b64 store: Ht[token=row16][hid=mt*16+quad*4+r]
        #pragma unroll
        for (int mt = 0; mt < 8; ++mt) {
            int hidb = ch * 128 + mt * 16 + quad * 4;
            f32x4 b1v = *(const f32x4*)(b1 + hidb);
            float h0 = gelu_fast(acc1[mt][0] + b1v[0]);
            float h1 = gelu_fast(acc1[mt][1] + b1v[1]);
            float h2 = gelu_fast(acc1[mt][2] + b1v[2]);
            float h3 = gelu_fast(acc1[mt][3] + b1v[3]);
            uint2 pk;
            pk.x = pack2bf(h0, h1);
            pk.y = pack2bf(h2, h3);
            *(uint2*)(Ht + row16 * MSTRIDE + mt * 16 + quad * 4) = pk;
        }
        LDS_FENCE();
        // FC2 partial: A = Ht token rows (b128), B = w2t c rows
        #pragma unroll
        for (int kt = 0; kt < 4; ++kt) {
            short8 a2 = *(const short8*)(Ht + row16 * MSTRIDE + kt * 32 + quad * 8);
            #pragma unroll
            for (int nt = 0; nt < 8; ++nt) {
                short8 b = *(const short8*)(w2t + (size_t)(nt * 16 + row16) * HID + ch * 128 + kt * 32 + quad * 8);
                acc2[nt] = __builtin_amdgcn_mfma_f32_16x16x32_bf16(a2, b, acc2[nt], 0, 0, 0);
            }
        }
        LDS_FENCE();
    }
    #pragma unroll
    for (int nt = 0; nt < 8; ++nt) {
        int col = nt * 16 + row16;
        float bb = b2[col];
        #pragma unroll
        for (int r = 0; r < 4; ++r) {
            size_t idx = (t0 + quad * 4 + r) * Cc + col;
            out[idx] = x1[idx] + bb + acc2[nt][r];
        }
    }
}

// ---------------------------------------------------------------------------
extern "C" void kernel_launch(void* const* d_in, const int* in_sizes, int n_in,
                              void* d_out, int out_size, void* d_ws, size_t ws_size,
                              hipStream_t stream) {
    const float* x     = (const float*)d_in[0];
    const float* n1g   = (const float*)d_in[1];
    const float* n1b   = (const float*)d_in[2];
    const float* qkvw  = (const float*)d_in[3];
    const float* qkvb  = (const float*)d_in[4];
    const float* projw = (const float*)d_in[5];
    const float* projb = (const float*)d_in[6];
    const float* rpb   = (const float*)d_in[7];
    const float* n2g   = (const float*)d_in[8];
    const float* n2b   = (const float*)d_in[9];
    const float* fc1w  = (const float*)d_in[10];
    const float* fc1b  = (const float*)d_in[11];
    const float* fc2w  = (const float*)d_in[12];
    const float* fc2b  = (const float*)d_in[13];
    float* out = (float*)d_out;

    char* ws = (char*)d_ws;
    short* qkv   = (short*)ws;
    float* x1    = (float*)(ws + 77070336);
    float* table = x1;  // dead until proj_ln2 writes x1 (attn reads it first)
    short* h     = (short*)(ws + 77070336 + 51380224);
    short* m     = h;
    short* o     = (short*)(ws + 77070336 + 51380224 + 25690112);
    short* qkvwT = (short*)(ws + 77070336 + 51380224 + 2 * 25690112);
    short* projwT= qkvwT + 384 * 128;
    short* fc1wT = projwT + 128 * 128;
    short* fc2wT = fc1wT + 512 * 128;

    conv_t<<<(128 * 384 + 255) / 256, 256, 0, stream>>>(qkvw, qkvwT, 128, 384);
    conv_t<<<(128 * 128 + 255) / 256, 256, 0, stream>>>(projw, projwT, 128, 128);
    conv_t<<<(128 * 512 + 255) / 256, 256, 0, stream>>>(fc1w, fc1wT, 128, 512);
    conv_t<<<(512 * 128 + 255) / 256, 256, 0, stream>>>(fc2w, fc2wT, 512, 128);
    build_table<<<256, 256, 0, stream>>>(rpb, table);

    ln1_gather<<<TOK / 4, 256, 0, stream>>>(x, n1g, n1b, h);
    qkv_mfma<<<TOK / 64, 256, 0, stream>>>(h, qkvwT, qkvb, qkv);
    attn_mfma<<<(TOK / Nn) * HEAD / 4, 256, 0, stream>>>(qkv, table, o);
    proj_ln2<<<TOK / 64, 256, 0, stream>>>(o, projwT, projb, x, n2g, n2b, x1, m);
    mlp_mfma<<<TOK / 64, 256, 0, stream>>>(m, fc1wT, fc1b, fc2wT, fc2b, x1, out);
}

// Round 5
// 392.201 us; speedup vs baseline: 1.4188x; 1.4188x over previous
//
#include <hip/hip_runtime.h>
#include <hip/hip_bf16.h>
#include <math.h>

#define Bb 32
#define Hh 56
#define Ww 56
#define Cc 128
#define HEAD 4
#define WS 7
#define SHIFT 3
#define Nn 49
#define NWw 64
#define HD 32
#define HID 512
#define TOK (Bb*Hh*Ww)
#define SCALEF 0.17677669529663687f
#define WSTRIDE 136   // shorts: 272 B = 17*16 -> 16B-aligned rows, conflict-light

typedef short short8 __attribute__((ext_vector_type(8)));
typedef float f32x4 __attribute__((ext_vector_type(4)));

__device__ __forceinline__ short f2bf(float f) {
    union { float f; unsigned u; } c; c.f = f;
    unsigned r = (c.u + 0x7fff + ((c.u >> 16) & 1)) >> 16;
    return (short)r;
}
__device__ __forceinline__ unsigned pack2bf(float a, float b) {
    return (unsigned)(unsigned short)f2bf(a) | ((unsigned)(unsigned short)f2bf(b) << 16);
}
__device__ __forceinline__ float gelu_fast(float x) {
    float x3 = x * x * x;
    float y = 0.7978845608f * (x + 0.044715f * x3);
    float e = __expf(2.f * y);
    float t = 1.f - 2.f / (e + 1.f);
    return 0.5f * x * (1.f + t);
}
#define LDS_FENCE() asm volatile("s_waitcnt lgkmcnt(0)" ::: "memory")

// ---------------------------------------------------------------------------
__global__ void conv_t(const float* __restrict__ in, short* __restrict__ out,
                       int K, int N) {
    int idx = blockIdx.x * 256 + threadIdx.x;
    if (idx >= K * N) return;
    int k = idx / N, n = idx % N;
    out[(size_t)n * K + k] = f2bf(in[idx]);
}

// ---------------------------------------------------------------------------
__global__ void build_table(const float* __restrict__ rpb, float* __restrict__ table) {
    int idx = blockIdx.x * 256 + threadIdx.x;
    if (idx >= 16 * 4096) return;
    int cell = idx & 4095, ch = idx >> 12;
    int cls = ch >> 2, hd = ch & 3;
    int row = cell >> 6, col = cell & 63;
    float v;
    if (row >= Nn || col >= Nn) v = -1e30f;
    else {
        int i1 = row / 7, j1 = row % 7, i2 = col / 7, j2 = col % 7;
        float bias = rpb[((i1 - i2 + 6) * 13 + (j1 - j2 + 6)) * HEAD + hd];
        int bh = cls >> 1, bw = cls & 1;
        int rn = bh ? (i1 < 4 ? 1 : 2) : 0;
        int cn = bw ? (j1 < 4 ? 1 : 2) : 0;
        int rm = bh ? (i2 < 4 ? 1 : 2) : 0;
        int cm = bw ? (j2 < 4 ? 1 : 2) : 0;
        v = bias + (((rn * 3 + cn) != (rm * 3 + cm)) ? -100.f : 0.f);
    }
    table[idx] = v;
}

// ---------------------------------------------------------------------------
__global__ __launch_bounds__(256) void ln1_gather(const float* __restrict__ x,
                                                  const float* __restrict__ g,
                                                  const float* __restrict__ b,
                                                  short* __restrict__ h) {
    int wave = threadIdx.x >> 6, lane = threadIdx.x & 63;
    int t = blockIdx.x * 4 + wave;
    int bimg = t / (NWw * Nn);
    int wrow = t % (NWw * Nn);
    int wi = wrow / Nn, n = wrow % Nn;
    int wh = wi >> 3, ww = wi & 7;
    int i = n / 7, j = n % 7;
    int sr = (wh * 7 + i + SHIFT) % Hh;
    int scol = (ww * 7 + j + SHIFT) % Ww;
    const float* xr = x + ((size_t)bimg * (Hh * Ww) + sr * Ww + scol) * Cc;
    float2 v = ((const float2*)xr)[lane];
    float s = v.x + v.y;
    #pragma unroll
    for (int m = 32; m; m >>= 1) s += __shfl_xor(s, m, 64);
    float mean = s * (1.f / 128.f);
    float dx = v.x - mean, dy = v.y - mean;
    float vs = dx * dx + dy * dy;
    #pragma unroll
    for (int m = 32; m; m >>= 1) vs += __shfl_xor(vs, m, 64);
    float inv = rsqrtf(vs * (1.f / 128.f) + 1e-5f);
    float2 gg = ((const float2*)g)[lane];
    float2 bb = ((const float2*)b)[lane];
    ((unsigned*)(h + (size_t)t * Cc))[lane] =
        pack2bf(dx * inv * gg.x + bb.x, dy * inv * gg.y + bb.y);
}

// ---------------------------------------------------------------------------
// QKV GEMM: 128 tokens/block, 32 tok/wave. Weights staged per 128-col chunk
// into LDS (stride 136); tokens held in registers; 2 MFMA per B ds_read.
// ---------------------------------------------------------------------------
__global__ __launch_bounds__(256) void qkv_mfma(const short* __restrict__ h,
                                                const short* __restrict__ wt,
                                                const float* __restrict__ bias,
                                                short* __restrict__ qkv) {
    __shared__ short Wc[128 * WSTRIDE];
    int tid = threadIdx.x;
    int wave = tid >> 6, lane = tid & 63;
    int row16 = lane & 15, quad = lane >> 4;
    size_t t0 = (size_t)blockIdx.x * 128 + wave * 32;
    short8 afr[2][4];
    #pragma unroll
    for (int mt = 0; mt < 2; ++mt)
        #pragma unroll
        for (int k = 0; k < 4; ++k)
            afr[mt][k] = *(const short8*)(h + (t0 + mt * 16 + row16) * Cc + k * 32 + quad * 8);
    int srow = tid >> 4, skof = (tid & 15) * 8;
    for (int ch = 0; ch < 3; ++ch) {
        __syncthreads();
        #pragma unroll
        for (int i = 0; i < 8; ++i) {
            int r = srow + i * 16;
            short8 w = *(const short8*)(wt + (size_t)(ch * 128 + r) * Cc + skof);
            *(short8*)(Wc + r * WSTRIDE + skof) = w;
        }
        __syncthreads();
        f32x4 acc[2][8];
        #pragma unroll
        for (int mt = 0; mt < 2; ++mt)
            #pragma unroll
            for (int n = 0; n < 8; ++n) acc[mt][n] = (f32x4)(0.f);
        #pragma unroll
        for (int k = 0; k < 4; ++k) {
            #pragma unroll
            for (int n = 0; n < 8; ++n) {
                short8 bfr = *(const short8*)(Wc + (n * 16 + row16) * WSTRIDE + k * 32 + quad * 8);
                acc[0][n] = __builtin_amdgcn_mfma_f32_16x16x32_bf16(afr[0][k], bfr, acc[0][n], 0, 0, 0);
                acc[1][n] = __builtin_amdgcn_mfma_f32_16x16x32_bf16(afr[1][k], bfr, acc[1][n], 0, 0, 0);
            }
        }
        #pragma unroll
        for (int mt = 0; mt < 2; ++mt)
            #pragma unroll
            for (int n = 0; n < 8; ++n) {
                int col = ch * 128 + n * 16 + row16;
                float bv = bias[col];
                #pragma unroll
                for (int r = 0; r < 4; ++r) {
                    float val = acc[mt][n][r] + bv;
                    if (ch == 0) val *= SCALEF;
                    qkv[(t0 + mt * 16 + quad * 4 + r) * 384 + col] = f2bf(val);
                }
            }
    }
}

// ---------------------------------------------------------------------------
// MFMA attention: one wave per (window, head). Unchanged from round 3.
// ---------------------------------------------------------------------------
__global__ __launch_bounds__(256) void attn_mfma(const short* __restrict__ qkv,
                                                 const float* __restrict__ table,
                                                 short* __restrict__ o) {
    __shared__ short Pbuf[4][64 * 72];
    __shared__ short Vbuf[4][32 * 72];
    int wave = threadIdx.x >> 6, lane = threadIdx.x & 63;
    int row16 = lane & 15, quad = lane >> 4;
    int unit = blockIdx.x * 4 + wave;
    int bw = unit >> 2, hd = unit & 3;
    int widx = bw & 63, wh = widx >> 3, ww = widx & 7;
    int cls = ((wh == 7) ? 2 : 0) | ((ww == 7) ? 1 : 0);
    const float* tb = table + ((size_t)(cls * 4 + hd)) * 4096;
    short* P = &Pbuf[wave][0];
    short* vt = &Vbuf[wave][0];
    const short* base = qkv + (size_t)bw * Nn * 384 + hd * HD;

    {
        int t = lane;
        if (t < Nn) {
            const short* vrow = base + (size_t)t * 384 + 256;
            #pragma unroll
            for (int d = 0; d < HD; d += 2) {
                unsigned pr = *(const unsigned*)(vrow + d);
                vt[d * 72 + t] = (short)(pr & 0xffff);
                vt[(d + 1) * 72 + t] = (short)(pr >> 16);
            }
        } else {
            #pragma unroll
            for (int d = 0; d < HD; ++d) vt[d * 72 + t] = 0;
        }
    }

    short8 qa[4], kb[4];
    #pragma unroll
    for (int mt = 0; mt < 4; ++mt) {
        int r = mt * 16 + row16;
        if (r < Nn) {
            qa[mt] = *(const short8*)(base + (size_t)r * 384 + quad * 8);
            kb[mt] = *(const short8*)(base + (size_t)r * 384 + 128 + quad * 8);
        } else {
            qa[mt] = (short8)(short)0;
            kb[mt] = (short8)(short)0;
        }
    }
    f32x4 s[4][4];
    #pragma unroll
    for (int mt = 0; mt < 4; ++mt)
        #pragma unroll
        for (int nt = 0; nt < 4; ++nt)
            s[mt][nt] = __builtin_amdgcn_mfma_f32_16x16x32_bf16(qa[mt], kb[nt], (f32x4)(0.f), 0, 0, 0);

    #pragma unroll
    for (int mt = 0; mt < 4; ++mt) {
        #pragma unroll
        for (int r = 0; r < 4; ++r) {
            int row = mt * 16 + quad * 4 + r;
            float mx = -1e30f;
            #pragma unroll
            for (int nt = 0; nt < 4; ++nt) {
                s[mt][nt][r] += tb[row * 64 + nt * 16 + row16];
                mx = fmaxf(mx, s[mt][nt][r]);
            }
            #pragma unroll
            for (int m = 1; m < 16; m <<= 1) mx = fmaxf(mx, __shfl_xor(mx, m, 64));
            float sm = 0.f;
            #pragma unroll
            for (int nt = 0; nt < 4; ++nt) {
                float e = __expf(s[mt][nt][r] - mx);
                s[mt][nt][r] = e;
                sm += e;
            }
            #pragma unroll
            for (int m = 1; m < 16; m <<= 1) sm += __shfl_xor(sm, m, 64);
            float inv = 1.f / sm;
            #pragma unroll
            for (int nt = 0; nt < 4; ++nt)
                P[row * 72 + nt * 16 + row16] = f2bf(s[mt][nt][r] * inv);
        }
    }
    LDS_FENCE();

    f32x4 oacc[4][2];
    #pragma unroll
    for (int mt = 0; mt < 4; ++mt)
        #pragma unroll
        for (int nt = 0; nt < 2; ++nt) oacc[mt][nt] = (f32x4)(0.f);
    #pragma unroll
    for (int kt = 0; kt < 2; ++kt) {
        short8 pa[4], vb[2];
        #pragma unroll
        for (int mt = 0; mt < 4; ++mt)
            pa[mt] = *(const short8*)(P + (mt * 16 + row16) * 72 + kt * 32 + quad * 8);
        #pragma unroll
        for (int nt = 0; nt < 2; ++nt)
            vb[nt] = *(const short8*)(vt + (nt * 16 + row16) * 72 + kt * 32 + quad * 8);
        #pragma unroll
        for (int mt = 0; mt < 4; ++mt)
            #pragma unroll
            for (int nt = 0; nt < 2; ++nt)
                oacc[mt][nt] = __builtin_amdgcn_mfma_f32_16x16x32_bf16(pa[mt], vb[nt], oacc[mt][nt], 0, 0, 0);
    }
    #pragma unroll
    for (int mt = 0; mt < 4; ++mt)
        #pragma unroll
        for (int nt = 0; nt < 2; ++nt)
            #pragma unroll
            for (int r = 0; r < 4; ++r) {
                int row = mt * 16 + quad * 4 + r;
                if (row < Nn)
                    o[((size_t)bw * Nn + row) * Cc + hd * HD + nt * 16 + row16] = f2bf(oacc[mt][nt][r]);
            }
}

// ---------------------------------------------------------------------------
// Proj: 128 tokens/block, 32 tok/wave, W staged once in LDS; scatter + LN2.
// ---------------------------------------------------------------------------
__global__ __launch_bounds__(256) void proj_ln2(const short* __restrict__ o,
                                                const short* __restrict__ wt,
                                                const float* __restrict__ pb,
                                                const float* __restrict__ x,
                                                const float* __restrict__ g2,
                                                const float* __restrict__ b2,
                                                float* __restrict__ x1,
                                                short* __restrict__ m) {
    __shared__ short Wc[128 * WSTRIDE];
    __shared__ int dest[128];
    int tid = threadIdx.x;
    int wave = tid >> 6, lane = tid & 63;
    int row16 = lane & 15, quad = lane >> 4;
    int s0 = blockIdx.x * 128;
    {
        int srow = tid >> 4, skof = (tid & 15) * 8;
        #pragma unroll
        for (int i = 0; i < 8; ++i) {
            int r = srow + i * 16;
            short8 w = *(const short8*)(wt + (size_t)r * Cc + skof);
            *(short8*)(Wc + r * WSTRIDE + skof) = w;
        }
    }
    if (tid < 128) {
        int st = s0 + tid;
        int bimg = st / (NWw * Nn);
        int rem = st % (NWw * Nn);
        int wi = rem / Nn, n = rem % Nn;
        int wh = wi >> 3, ww = wi & 7;
        int i = n / 7, j = n % 7;
        int dr = (wh * 7 + i + SHIFT) % Hh;
        int dc = (ww * 7 + j + SHIFT) % Ww;
        dest[tid] = bimg * (Hh * Ww) + dr * Ww + dc;
    }
    __syncthreads();
    int r0w = wave * 32;
    short8 afr[2][4];
    #pragma unroll
    for (int mt = 0; mt < 2; ++mt)
        #pragma unroll
        for (int k = 0; k < 4; ++k)
            afr[mt][k] = *(const short8*)(o + ((size_t)s0 + r0w + mt * 16 + row16) * Cc + k * 32 + quad * 8);
    f32x4 acc[2][8];
    #pragma unroll
    for (int mt = 0; mt < 2; ++mt)
        #pragma unroll
        for (int n = 0; n < 8; ++n) acc[mt][n] = (f32x4)(0.f);
    #pragma unroll
    for (int k = 0; k < 4; ++k) {
        #pragma unroll
        for (int n = 0; n < 8; ++n) {
            short8 bfr = *(const short8*)(Wc + (n * 16 + row16) * WSTRIDE + k * 32 + quad * 8);
            acc[0][n] = __builtin_amdgcn_mfma_f32_16x16x32_bf16(afr[0][k], bfr, acc[0][n], 0, 0, 0);
            acc[1][n] = __builtin_amdgcn_mfma_f32_16x16x32_bf16(afr[1][k], bfr, acc[1][n], 0, 0, 0);
        }
    }
    float gv[8], bv[8], pbv[8];
    #pragma unroll
    for (int n = 0; n < 8; ++n) {
        int col = n * 16 + row16;
        gv[n] = g2[col]; bv[n] = b2[col]; pbv[n] = pb[col];
    }
    #pragma unroll
    for (int mt = 0; mt < 2; ++mt)
        #pragma unroll
        for (int r = 0; r < 4; ++r) {
            int di = dest[r0w + mt * 16 + quad * 4 + r];
            #pragma unroll
            for (int n = 0; n < 8; ++n)
                acc[mt][n][r] += x[(size_t)di * Cc + n * 16 + row16] + pbv[n];
            float sum = 0.f;
            #pragma unroll
            for (int n = 0; n < 8; ++n) sum += acc[mt][n][r];
            #pragma unroll
            for (int mk = 1; mk < 16; mk <<= 1) sum += __shfl_xor(sum, mk, 64);
            float mean = sum * (1.f / 128.f);
            float var = 0.f;
            #pragma unroll
            for (int n = 0; n < 8; ++n) {
                float d = acc[mt][n][r] - mean;
                var += d * d;
            }
            #pragma unroll
            for (int mk = 1; mk < 16; mk <<= 1) var += __shfl_xor(var, mk, 64);
            float inv = rsqrtf(var * (1.f / 128.f) + 1e-5f);
            #pragma unroll
            for (int n = 0; n < 8; ++n) {
                size_t idx = (size_t)di * Cc + n * 16 + row16;
                float v = acc[mt][n][r];
                x1[idx] = v;
                m[idx] = f2bf((v - mean) * inv * gv[n] + bv[n]);
            }
        }
}

// ---------------------------------------------------------------------------
// Fused MLP: 128 tokens/block, 32 tok/wave. 8 chunks of 64 hidden:
//   W1 chunk staged in LDS (all waves share); FC1 C[m=hid][n=tok];
//   GELU -> per-wave H [32 tok][72] in LDS (b64 writes, lgkm fence only);
//   FC2 A=H rows (ds_read_b128), B=w2t streamed from L2 (2:1 MFMA:load).
// ---------------------------------------------------------------------------
#define HSTRIDE 72
__global__ __launch_bounds__(256) void mlp_mfma(const short* __restrict__ m,
                                                const short* __restrict__ w1t,
                                                const float* __restrict__ b1,
                                                const short* __restrict__ w2t,
                                                const float* __restrict__ b2,
                                                const float* __restrict__ x1,
                                                float* __restrict__ out) {
    __shared__ short W1c[64 * WSTRIDE];
    __shared__ short Hs[4][32 * HSTRIDE];
    int tid = threadIdx.x;
    int wave = tid >> 6, lane = tid & 63;
    int row16 = lane & 15, quad = lane >> 4;
    size_t t0 = (size_t)blockIdx.x * 128 + wave * 32;
    short* Ht = &Hs[wave][0];
    short8 bfr[2][4];
    #pragma unroll
    for (int nt = 0; nt < 2; ++nt)
        #pragma unroll
        for (int k = 0; k < 4; ++k)
            bfr[nt][k] = *(const short8*)(m + (t0 + nt * 16 + row16) * Cc + k * 32 + quad * 8);
    f32x4 acc2[2][8];
    #pragma unroll
    for (int mt = 0; mt < 2; ++mt)
        #pragma unroll
        for (int n = 0; n < 8; ++n) acc2[mt][n] = (f32x4)(0.f);
    int srow = tid >> 4, skof = (tid & 15) * 8;
    for (int ch = 0; ch < 8; ++ch) {
        __syncthreads();
        #pragma unroll
        for (int i = 0; i < 4; ++i) {
            int r = srow + i * 16;
            short8 w = *(const short8*)(w1t + (size_t)(ch * 64 + r) * Cc + skof);
            *(short8*)(W1c + r * WSTRIDE + skof) = w;
        }
        __syncthreads();
        // FC1: C[m=hid(64)][n=tok(32)]
        f32x4 acc1[4][2];
        #pragma unroll
        for (int mt = 0; mt < 4; ++mt)
            #pragma unroll
            for (int nt = 0; nt < 2; ++nt) acc1[mt][nt] = (f32x4)(0.f);
        #pragma unroll
        for (int k = 0; k < 4; ++k) {
            #pragma unroll
            for (int mt = 0; mt < 4; ++mt) {
                short8 a = *(const short8*)(W1c + (mt * 16 + row16) * WSTRIDE + k * 32 + quad * 8);
                acc1[mt][0] = __builtin_amdgcn_mfma_f32_16x16x32_bf16(a, bfr[0][k], acc1[mt][0], 0, 0, 0);
                acc1[mt][1] = __builtin_amdgcn_mfma_f32_16x16x32_bf16(a, bfr[1][k], acc1[mt][1], 0, 0, 0);
            }
        }
        // GELU -> H^T (per-wave): H[tok][hid]
        #pragma unroll
        for (int mt = 0; mt < 4; ++mt) {
            int hidb = ch * 64 + mt * 16 + quad * 4;
            f32x4 b1v = *(const f32x4*)(b1 + hidb);
            #pragma unroll
            for (int nt = 0; nt < 2; ++nt) {
                float h0 = gelu_fast(acc1[mt][nt][0] + b1v[0]);
                float h1 = gelu_fast(acc1[mt][nt][1] + b1v[1]);
                float h2 = gelu_fast(acc1[mt][nt][2] + b1v[2]);
                float h3 = gelu_fast(acc1[mt][nt][3] + b1v[3]);
                uint2 pk;
                pk.x = pack2bf(h0, h1);
                pk.y = pack2bf(h2, h3);
                *(uint2*)(Ht + (nt * 16 + row16) * HSTRIDE + mt * 16 + quad * 4) = pk;
            }
        }
        LDS_FENCE();
        // FC2 partial over k = [ch*64, ch*64+64)
        #pragma unroll
        for (int kk = 0; kk < 2; ++kk) {
            short8 ha[2];
            #pragma unroll
            for (int mt = 0; mt < 2; ++mt)
                ha[mt] = *(const short8*)(Ht + (mt * 16 + row16) * HSTRIDE + kk * 32 + quad * 8);
            #pragma unroll
            for (int n = 0; n < 8; ++n) {
                short8 wb = *(const short8*)(w2t + (size_t)(n * 16 + row16) * HID + ch * 64 + kk * 32 + quad * 8);
                acc2[0][n] = __builtin_amdgcn_mfma_f32_16x16x32_bf16(ha[0], wb, acc2[0][n], 0, 0, 0);
                acc2[1][n] = __builtin_amdgcn_mfma_f32_16x16x32_bf16(ha[1], wb, acc2[1][n], 0, 0, 0);
            }
        }
    }
    #pragma unroll
    for (int mt = 0; mt < 2; ++mt)
        #pragma unroll
        for (int n = 0; n < 8; ++n) {
            int col = n * 16 + row16;
            float bb = b2[col];
            #pragma unroll
            for (int r = 0; r < 4; ++r) {
                size_t idx = (t0 + mt * 16 + quad * 4 + r) * Cc + col;
                out[idx] = x1[idx] + bb + acc2[mt][n][r];
            }
        }
}

// ---------------------------------------------------------------------------
extern "C" void kernel_launch(void* const* d_in, const int* in_sizes, int n_in,
                              void* d_out, int out_size, void* d_ws, size_t ws_size,
                              hipStream_t stream) {
    const float* x     = (const float*)d_in[0];
    const float* n1g   = (const float*)d_in[1];
    const float* n1b   = (const float*)d_in[2];
    const float* qkvw  = (const float*)d_in[3];
    const float* qkvb  = (const float*)d_in[4];
    const float* projw = (const float*)d_in[5];
    const float* projb = (const float*)d_in[6];
    const float* rpb   = (const float*)d_in[7];
    const float* n2g   = (const float*)d_in[8];
    const float* n2b   = (const float*)d_in[9];
    const float* fc1w  = (const float*)d_in[10];
    const float* fc1b  = (const float*)d_in[11];
    const float* fc2w  = (const float*)d_in[12];
    const float* fc2b  = (const float*)d_in[13];
    float* out = (float*)d_out;

    char* ws = (char*)d_ws;
    short* qkv   = (short*)ws;
    float* x1    = (float*)(ws + 77070336);
    float* table = x1;  // dead until proj_ln2 writes x1 (attn reads it first)
    short* h     = (short*)(ws + 77070336 + 51380224);
    short* m     = h;
    short* o     = (short*)(ws + 77070336 + 51380224 + 25690112);
    short* qkvwT = (short*)(ws + 77070336 + 51380224 + 2 * 25690112);
    short* projwT= qkvwT + 384 * 128;
    short* fc1wT = projwT + 128 * 128;
    short* fc2wT = fc1wT + 512 * 128;

    conv_t<<<(128 * 384 + 255) / 256, 256, 0, stream>>>(qkvw, qkvwT, 128, 384);
    conv_t<<<(128 * 128 + 255) / 256, 256, 0, stream>>>(projw, projwT, 128, 128);
    conv_t<<<(128 * 512 + 255) / 256, 256, 0, stream>>>(fc1w, fc1wT, 128, 512);
    conv_t<<<(512 * 128 + 255) / 256, 256, 0, stream>>>(fc2w, fc2wT, 512, 128);
    build_table<<<256, 256, 0, stream>>>(rpb, table);

    ln1_gather<<<TOK / 4, 256, 0, stream>>>(x, n1g, n1b, h);
    qkv_mfma<<<TOK / 128, 256, 0, stream>>>(h, qkvwT, qkvb, qkv);
    attn_mfma<<<(TOK / Nn) * HEAD / 4, 256, 0, stream>>>(qkv, table, o);
    proj_ln2<<<TOK / 128, 256, 0, stream>>>(o, projwT, projb, x, n2g, n2b, x1, m);
    mlp_mfma<<<TOK / 128, 256, 0, stream>>>(m, fc1wT, fc1b, fc2wT, fc2b, x1, out);
}

// Round 6
// 378.918 us; speedup vs baseline: 1.4686x; 1.0351x over previous
//
#include <hip/hip_runtime.h>
#include <hip/hip_bf16.h>
#include <math.h>

#define Bb 32
#define Hh 56
#define Ww 56
#define Cc 128
#define HEAD 4
#define WS 7
#define SHIFT 3
#define Nn 49
#define NWw 64
#define HD 32
#define HID 512
#define TOK (Bb*Hh*Ww)
#define SCALEF 0.17677669529663687f
#define WSTRIDE 136   // shorts: 272 B rows -> 16B-aligned, 2-way-max conflicts

typedef short short8 __attribute__((ext_vector_type(8)));
typedef float f32x4 __attribute__((ext_vector_type(4)));

__device__ __forceinline__ short f2bf(float f) {
    union { float f; unsigned u; } c; c.f = f;
    unsigned r = (c.u + 0x7fff + ((c.u >> 16) & 1)) >> 16;
    return (short)r;
}
__device__ __forceinline__ unsigned pack2bf(float a, float b) {
    return (unsigned)(unsigned short)f2bf(a) | ((unsigned)(unsigned short)f2bf(b) << 16);
}
__device__ __forceinline__ float gelu_fast(float x) {
    float x3 = x * x * x;
    float y = 0.7978845608f * (x + 0.044715f * x3);
    float e = __expf(2.f * y);
    float t = 1.f - 2.f / (e + 1.f);
    return 0.5f * x * (1.f + t);
}
#define LDS_FENCE() asm volatile("s_waitcnt lgkmcnt(0)" ::: "memory")

// ---------------------------------------------------------------------------
__global__ void conv_t(const float* __restrict__ in, short* __restrict__ out,
                       int K, int N) {
    int idx = blockIdx.x * 256 + threadIdx.x;
    if (idx >= K * N) return;
    int k = idx / N, n = idx % N;
    out[(size_t)n * K + k] = f2bf(in[idx]);
}

// ---------------------------------------------------------------------------
__global__ void build_table(const float* __restrict__ rpb, float* __restrict__ table) {
    int idx = blockIdx.x * 256 + threadIdx.x;
    if (idx >= 16 * 4096) return;
    int cell = idx & 4095, ch = idx >> 12;
    int cls = ch >> 2, hd = ch & 3;
    int row = cell >> 6, col = cell & 63;
    float v;
    if (row >= Nn || col >= Nn) v = -1e30f;
    else {
        int i1 = row / 7, j1 = row % 7, i2 = col / 7, j2 = col % 7;
        float bias = rpb[((i1 - i2 + 6) * 13 + (j1 - j2 + 6)) * HEAD + hd];
        int bh = cls >> 1, bw = cls & 1;
        int rn = bh ? (i1 < 4 ? 1 : 2) : 0;
        int cn = bw ? (j1 < 4 ? 1 : 2) : 0;
        int rm = bh ? (i2 < 4 ? 1 : 2) : 0;
        int cm = bw ? (j2 < 4 ? 1 : 2) : 0;
        v = bias + (((rn * 3 + cn) != (rm * 3 + cm)) ? -100.f : 0.f);
    }
    table[idx] = v;
}

// ---------------------------------------------------------------------------
__global__ __launch_bounds__(256) void ln1_gather(const float* __restrict__ x,
                                                  const float* __restrict__ g,
                                                  const float* __restrict__ b,
                                                  short* __restrict__ h) {
    int wave = threadIdx.x >> 6, lane = threadIdx.x & 63;
    int t = blockIdx.x * 4 + wave;
    int bimg = t / (NWw * Nn);
    int wrow = t % (NWw * Nn);
    int wi = wrow / Nn, n = wrow % Nn;
    int wh = wi >> 3, ww = wi & 7;
    int i = n / 7, j = n % 7;
    int sr = (wh * 7 + i + SHIFT) % Hh;
    int scol = (ww * 7 + j + SHIFT) % Ww;
    const float* xr = x + ((size_t)bimg * (Hh * Ww) + sr * Ww + scol) * Cc;
    float2 v = ((const float2*)xr)[lane];
    float s = v.x + v.y;
    #pragma unroll
    for (int m = 32; m; m >>= 1) s += __shfl_xor(s, m, 64);
    float mean = s * (1.f / 128.f);
    float dx = v.x - mean, dy = v.y - mean;
    float vs = dx * dx + dy * dy;
    #pragma unroll
    for (int m = 32; m; m >>= 1) vs += __shfl_xor(vs, m, 64);
    float inv = rsqrtf(vs * (1.f / 128.f) + 1e-5f);
    float2 gg = ((const float2*)g)[lane];
    float2 bb = ((const float2*)b)[lane];
    ((unsigned*)(h + (size_t)t * Cc))[lane] =
        pack2bf(dx * inv * gg.x + bb.x, dy * inv * gg.y + bb.y);
}

// ---------------------------------------------------------------------------
// QKV GEMM: 64 tokens/block (16/wave), grid 1568. W chunk staged in LDS.
// ---------------------------------------------------------------------------
__global__ __launch_bounds__(256) void qkv_mfma(const short* __restrict__ h,
                                                const short* __restrict__ wt,
                                                const float* __restrict__ bias,
                                                short* __restrict__ qkv) {
    __shared__ short Wc[128 * WSTRIDE];
    int tid = threadIdx.x;
    int wave = tid >> 6, lane = tid & 63;
    int row16 = lane & 15, quad = lane >> 4;
    size_t t0 = (size_t)blockIdx.x * 64 + wave * 16;
    short8 afr[4];
    #pragma unroll
    for (int k = 0; k < 4; ++k)
        afr[k] = *(const short8*)(h + (t0 + row16) * Cc + k * 32 + quad * 8);
    int srow = tid >> 4, skof = (tid & 15) * 8;
    for (int ch = 0; ch < 3; ++ch) {
        __syncthreads();
        #pragma unroll
        for (int i = 0; i < 8; ++i) {
            int r = srow + i * 16;
            short8 w = *(const short8*)(wt + (size_t)(ch * 128 + r) * Cc + skof);
            *(short8*)(Wc + r * WSTRIDE + skof) = w;
        }
        __syncthreads();
        f32x4 acc[8];
        #pragma unroll
        for (int n = 0; n < 8; ++n) acc[n] = (f32x4)(0.f);
        #pragma unroll
        for (int k = 0; k < 4; ++k) {
            #pragma unroll
            for (int n = 0; n < 8; ++n) {
                short8 bfr = *(const short8*)(Wc + (n * 16 + row16) * WSTRIDE + k * 32 + quad * 8);
                acc[n] = __builtin_amdgcn_mfma_f32_16x16x32_bf16(afr[k], bfr, acc[n], 0, 0, 0);
            }
        }
        #pragma unroll
        for (int n = 0; n < 8; ++n) {
            int col = ch * 128 + n * 16 + row16;
            float bv = bias[col];
            #pragma unroll
            for (int r = 0; r < 4; ++r) {
                float val = acc[n][r] + bv;
                if (ch == 0) val *= SCALEF;
                qkv[(t0 + quad * 4 + r) * 384 + col] = f2bf(val);
            }
        }
    }
}

// ---------------------------------------------------------------------------
// MFMA attention: one wave per (window, head); 2 waves/block for LDS-bounded
// occupancy (27.6 KB/block -> 5 blocks/CU).
// ---------------------------------------------------------------------------
__global__ __launch_bounds__(128) void attn_mfma(const short* __restrict__ qkv,
                                                 const float* __restrict__ table,
                                                 short* __restrict__ o) {
    __shared__ short Pbuf[2][64 * 72];
    __shared__ short Vbuf[2][32 * 72];
    int wave = threadIdx.x >> 6, lane = threadIdx.x & 63;
    int row16 = lane & 15, quad = lane >> 4;
    int unit = blockIdx.x * 2 + wave;
    int bw = unit >> 2, hd = unit & 3;
    int widx = bw & 63, wh = widx >> 3, ww = widx & 7;
    int cls = ((wh == 7) ? 2 : 0) | ((ww == 7) ? 1 : 0);
    const float* tb = table + ((size_t)(cls * 4 + hd)) * 4096;
    short* P = &Pbuf[wave][0];
    short* vt = &Vbuf[wave][0];
    const short* base = qkv + (size_t)bw * Nn * 384 + hd * HD;

    {
        int t = lane;
        if (t < Nn) {
            const short* vrow = base + (size_t)t * 384 + 256;
            #pragma unroll
            for (int d = 0; d < HD; d += 2) {
                unsigned pr = *(const unsigned*)(vrow + d);
                vt[d * 72 + t] = (short)(pr & 0xffff);
                vt[(d + 1) * 72 + t] = (short)(pr >> 16);
            }
        } else {
            #pragma unroll
            for (int d = 0; d < HD; ++d) vt[d * 72 + t] = 0;
        }
    }

    short8 qa[4], kb[4];
    #pragma unroll
    for (int mt = 0; mt < 4; ++mt) {
        int r = mt * 16 + row16;
        if (r < Nn) {
            qa[mt] = *(const short8*)(base + (size_t)r * 384 + quad * 8);
            kb[mt] = *(const short8*)(base + (size_t)r * 384 + 128 + quad * 8);
        } else {
            qa[mt] = (short8)(short)0;
            kb[mt] = (short8)(short)0;
        }
    }
    f32x4 s[4][4];
    #pragma unroll
    for (int mt = 0; mt < 4; ++mt)
        #pragma unroll
        for (int nt = 0; nt < 4; ++nt)
            s[mt][nt] = __builtin_amdgcn_mfma_f32_16x16x32_bf16(qa[mt], kb[nt], (f32x4)(0.f), 0, 0, 0);

    #pragma unroll
    for (int mt = 0; mt < 4; ++mt) {
        #pragma unroll
        for (int r = 0; r < 4; ++r) {
            int row = mt * 16 + quad * 4 + r;
            float mx = -1e30f;
            #pragma unroll
            for (int nt = 0; nt < 4; ++nt) {
                s[mt][nt][r] += tb[row * 64 + nt * 16 + row16];
                mx = fmaxf(mx, s[mt][nt][r]);
            }
            #pragma unroll
            for (int m = 1; m < 16; m <<= 1) mx = fmaxf(mx, __shfl_xor(mx, m, 64));
            float sm = 0.f;
            #pragma unroll
            for (int nt = 0; nt < 4; ++nt) {
                float e = __expf(s[mt][nt][r] - mx);
                s[mt][nt][r] = e;
                sm += e;
            }
            #pragma unroll
            for (int m = 1; m < 16; m <<= 1) sm += __shfl_xor(sm, m, 64);
            float inv = 1.f / sm;
            #pragma unroll
            for (int nt = 0; nt < 4; ++nt)
                P[row * 72 + nt * 16 + row16] = f2bf(s[mt][nt][r] * inv);
        }
    }
    LDS_FENCE();

    f32x4 oacc[4][2];
    #pragma unroll
    for (int mt = 0; mt < 4; ++mt)
        #pragma unroll
        for (int nt = 0; nt < 2; ++nt) oacc[mt][nt] = (f32x4)(0.f);
    #pragma unroll
    for (int kt = 0; kt < 2; ++kt) {
        short8 pa[4], vb[2];
        #pragma unroll
        for (int mt = 0; mt < 4; ++mt)
            pa[mt] = *(const short8*)(P + (mt * 16 + row16) * 72 + kt * 32 + quad * 8);
        #pragma unroll
        for (int nt = 0; nt < 2; ++nt)
            vb[nt] = *(const short8*)(vt + (nt * 16 + row16) * 72 + kt * 32 + quad * 8);
        #pragma unroll
        for (int mt = 0; mt < 4; ++mt)
            #pragma unroll
            for (int nt = 0; nt < 2; ++nt)
                oacc[mt][nt] = __builtin_amdgcn_mfma_f32_16x16x32_bf16(pa[mt], vb[nt], oacc[mt][nt], 0, 0, 0);
    }
    #pragma unroll
    for (int mt = 0; mt < 4; ++mt)
        #pragma unroll
        for (int nt = 0; nt < 2; ++nt)
            #pragma unroll
            for (int r = 0; r < 4; ++r) {
                int row = mt * 16 + quad * 4 + r;
                if (row < Nn)
                    o[((size_t)bw * Nn + row) * Cc + hd * HD + nt * 16 + row16] = f2bf(oacc[mt][nt][r]);
            }
}

// ---------------------------------------------------------------------------
// Proj: 64 tokens/block (16/wave), grid 1568. W staged once; scatter + LN2.
// ---------------------------------------------------------------------------
__global__ __launch_bounds__(256) void proj_ln2(const short* __restrict__ o,
                                                const short* __restrict__ wt,
                                                const float* __restrict__ pb,
                                                const float* __restrict__ x,
                                                const float* __restrict__ g2,
                                                const float* __restrict__ b2,
                                                float* __restrict__ x1,
                                                short* __restrict__ m) {
    __shared__ short Wc[128 * WSTRIDE];
    __shared__ int dest[64];
    int tid = threadIdx.x;
    int wave = tid >> 6, lane = tid & 63;
    int row16 = lane & 15, quad = lane >> 4;
    int s0 = blockIdx.x * 64;
    {
        int srow = tid >> 4, skof = (tid & 15) * 8;
        #pragma unroll
        for (int i = 0; i < 8; ++i) {
            int r = srow + i * 16;
            short8 w = *(const short8*)(wt + (size_t)r * Cc + skof);
            *(short8*)(Wc + r * WSTRIDE + skof) = w;
        }
    }
    if (tid < 64) {
        int st = s0 + tid;
        int bimg = st / (NWw * Nn);
        int rem = st % (NWw * Nn);
        int wi = rem / Nn, n = rem % Nn;
        int wh = wi >> 3, ww = wi & 7;
        int i = n / 7, j = n % 7;
        int dr = (wh * 7 + i + SHIFT) % Hh;
        int dc = (ww * 7 + j + SHIFT) % Ww;
        dest[tid] = bimg * (Hh * Ww) + dr * Ww + dc;
    }
    __syncthreads();
    int r0w = wave * 16;
    short8 afr[4];
    #pragma unroll
    for (int k = 0; k < 4; ++k)
        afr[k] = *(const short8*)(o + ((size_t)s0 + r0w + row16) * Cc + k * 32 + quad * 8);
    f32x4 acc[8];
    #pragma unroll
    for (int n = 0; n < 8; ++n) acc[n] = (f32x4)(0.f);
    #pragma unroll
    for (int k = 0; k < 4; ++k) {
        #pragma unroll
        for (int n = 0; n < 8; ++n) {
            short8 bfr = *(const short8*)(Wc + (n * 16 + row16) * WSTRIDE + k * 32 + quad * 8);
            acc[n] = __builtin_amdgcn_mfma_f32_16x16x32_bf16(afr[k], bfr, acc[n], 0, 0, 0);
        }
    }
    float gv[8], bv[8], pbv[8];
    #pragma unroll
    for (int n = 0; n < 8; ++n) {
        int col = n * 16 + row16;
        gv[n] = g2[col]; bv[n] = b2[col]; pbv[n] = pb[col];
    }
    #pragma unroll
    for (int r = 0; r < 4; ++r) {
        int di = dest[r0w + quad * 4 + r];
        #pragma unroll
        for (int n = 0; n < 8; ++n)
            acc[n][r] += x[(size_t)di * Cc + n * 16 + row16] + pbv[n];
        float sum = 0.f;
        #pragma unroll
        for (int n = 0; n < 8; ++n) sum += acc[n][r];
        #pragma unroll
        for (int mk = 1; mk < 16; mk <<= 1) sum += __shfl_xor(sum, mk, 64);
        float mean = sum * (1.f / 128.f);
        float var = 0.f;
        #pragma unroll
        for (int n = 0; n < 8; ++n) {
            float d = acc[n][r] - mean;
            var += d * d;
        }
        #pragma unroll
        for (int mk = 1; mk < 16; mk <<= 1) var += __shfl_xor(var, mk, 64);
        float inv = rsqrtf(var * (1.f / 128.f) + 1e-5f);
        #pragma unroll
        for (int n = 0; n < 8; ++n) {
            size_t idx = (size_t)di * Cc + n * 16 + row16;
            float v = acc[n][r];
            x1[idx] = v;
            m[idx] = f2bf((v - mean) * inv * gv[n] + bv[n]);
        }
    }
}

// ---------------------------------------------------------------------------
// Fused MLP: 64 tokens/block (16/wave), grid 1568. W1 64-hid chunks staged in
// LDS; per-wave H round-trip; FC2 W2 streamed from L2. LDS 26.6 KB/block.
// ---------------------------------------------------------------------------
#define HSTRIDE 72
__global__ __launch_bounds__(256) void mlp_mfma(const short* __restrict__ m,
                                                const short* __restrict__ w1t,
                                                const float* __restrict__ b1,
                                                const short* __restrict__ w2t,
                                                const float* __restrict__ b2,
                                                const float* __restrict__ x1,
                                                float* __restrict__ out) {
    __shared__ short W1c[64 * WSTRIDE];
    __shared__ short Hs[4][16 * HSTRIDE];
    int tid = threadIdx.x;
    int wave = tid >> 6, lane = tid & 63;
    int row16 = lane & 15, quad = lane >> 4;
    size_t t0 = (size_t)blockIdx.x * 64 + wave * 16;
    short* Ht = &Hs[wave][0];
    short8 bfr[4];
    #pragma unroll
    for (int k = 0; k < 4; ++k)
        bfr[k] = *(const short8*)(m + (t0 + row16) * Cc + k * 32 + quad * 8);
    f32x4 acc2[8];
    #pragma unroll
    for (int n = 0; n < 8; ++n) acc2[n] = (f32x4)(0.f);
    int srow = tid >> 4, skof = (tid & 15) * 8;
    for (int ch = 0; ch < 8; ++ch) {
        __syncthreads();
        #pragma unroll
        for (int i = 0; i < 4; ++i) {
            int r = srow + i * 16;
            short8 w = *(const short8*)(w1t + (size_t)(ch * 64 + r) * Cc + skof);
            *(short8*)(W1c + r * WSTRIDE + skof) = w;
        }
        __syncthreads();
        // FC1: C[m=hid(64)][n=tok(16)]
        f32x4 acc1[4];
        #pragma unroll
        for (int mt = 0; mt < 4; ++mt) acc1[mt] = (f32x4)(0.f);
        #pragma unroll
        for (int k = 0; k < 4; ++k) {
            #pragma unroll
            for (int mt = 0; mt < 4; ++mt) {
                short8 a = *(const short8*)(W1c + (mt * 16 + row16) * WSTRIDE + k * 32 + quad * 8);
                acc1[mt] = __builtin_amdgcn_mfma_f32_16x16x32_bf16(a, bfr[k], acc1[mt], 0, 0, 0);
            }
        }
        // GELU -> per-wave H[tok(16)][hid(64)]
        #pragma unroll
        for (int mt = 0; mt < 4; ++mt) {
            int hidb = ch * 64 + mt * 16 + quad * 4;
            f32x4 b1v = *(const f32x4*)(b1 + hidb);
            float h0 = gelu_fast(acc1[mt][0] + b1v[0]);
            float h1 = gelu_fast(acc1[mt][1] + b1v[1]);
            float h2 = gelu_fast(acc1[mt][2] + b1v[2]);
            float h3 = gelu_fast(acc1[mt][3] + b1v[3]);
            uint2 pk;
            pk.x = pack2bf(h0, h1);
            pk.y = pack2bf(h2, h3);
            *(uint2*)(Ht + row16 * HSTRIDE + mt * 16 + quad * 4) = pk;
        }
        LDS_FENCE();
        // FC2 partial over k = [ch*64, ch*64+64)
        #pragma unroll
        for (int kk = 0; kk < 2; ++kk) {
            short8 ha = *(const short8*)(Ht + row16 * HSTRIDE + kk * 32 + quad * 8);
            #pragma unroll
            for (int n = 0; n < 8; ++n) {
                short8 wb = *(const short8*)(w2t + (size_t)(n * 16 + row16) * HID + ch * 64 + kk * 32 + quad * 8);
                acc2[n] = __builtin_amdgcn_mfma_f32_16x16x32_bf16(ha, wb, acc2[n], 0, 0, 0);
            }
        }
    }
    #pragma unroll
    for (int n = 0; n < 8; ++n) {
        int col = n * 16 + row16;
        float bb = b2[col];
        #pragma unroll
        for (int r = 0; r < 4; ++r) {
            size_t idx = (t0 + quad * 4 + r) * Cc + col;
            out[idx] = x1[idx] + bb + acc2[n][r];
        }
    }
}

// ---------------------------------------------------------------------------
extern "C" void kernel_launch(void* const* d_in, const int* in_sizes, int n_in,
                              void* d_out, int out_size, void* d_ws, size_t ws_size,
                              hipStream_t stream) {
    const float* x     = (const float*)d_in[0];
    const float* n1g   = (const float*)d_in[1];
    const float* n1b   = (const float*)d_in[2];
    const float* qkvw  = (const float*)d_in[3];
    const float* qkvb  = (const float*)d_in[4];
    const float* projw = (const float*)d_in[5];
    const float* projb = (const float*)d_in[6];
    const float* rpb   = (const float*)d_in[7];
    const float* n2g   = (const float*)d_in[8];
    const float* n2b   = (const float*)d_in[9];
    const float* fc1w  = (const float*)d_in[10];
    const float* fc1b  = (const float*)d_in[11];
    const float* fc2w  = (const float*)d_in[12];
    const float* fc2b  = (const float*)d_in[13];
    float* out = (float*)d_out;

    char* ws = (char*)d_ws;
    short* qkv   = (short*)ws;
    float* x1    = (float*)(ws + 77070336);
    float* table = x1;  // dead until proj_ln2 writes x1 (attn reads it first)
    short* h     = (short*)(ws + 77070336 + 51380224);
    short* m     = h;
    short* o     = (short*)(ws + 77070336 + 51380224 + 25690112);
    short* qkvwT = (short*)(ws + 77070336 + 51380224 + 2 * 25690112);
    short* projwT= qkvwT + 384 * 128;
    short* fc1wT = projwT + 128 * 128;
    short* fc2wT = fc1wT + 512 * 128;

    conv_t<<<(128 * 384 + 255) / 256, 256, 0, stream>>>(qkvw, qkvwT, 128, 384);
    conv_t<<<(128 * 128 + 255) / 256, 256, 0, stream>>>(projw, projwT, 128, 128);
    conv_t<<<(128 * 512 + 255) / 256, 256, 0, stream>>>(fc1w, fc1wT, 128, 512);
    conv_t<<<(512 * 128 + 255) / 256, 256, 0, stream>>>(fc2w, fc2wT, 512, 128);
    build_table<<<256, 256, 0, stream>>>(rpb, table);

    ln1_gather<<<TOK / 4, 256, 0, stream>>>(x, n1g, n1b, h);
    qkv_mfma<<<TOK / 64, 256, 0, stream>>>(h, qkvwT, qkvb, qkv);
    attn_mfma<<<(TOK / Nn) * HEAD / 2, 128, 0, stream>>>(qkv, table, o);
    proj_ln2<<<TOK / 64, 256, 0, stream>>>(o, projwT, projb, x, n2g, n2b, x1, m);
    mlp_mfma<<<TOK / 64, 256, 0, stream>>>(m, fc1wT, fc1b, fc2wT, fc2b, x1, out);
}

// Round 7
// 356.695 us; speedup vs baseline: 1.5601x; 1.0623x over previous
//
#include <hip/hip_runtime.h>
#include <hip/hip_bf16.h>
#include <math.h>

#define Bb 32
#define Hh 56
#define Ww 56
#define Cc 128
#define HEAD 4
#define WS 7
#define SHIFT 3
#define Nn 49
#define NWw 64
#define HD 32
#define HID 512
#define TOK (Bb*Hh*Ww)
#define SCALEF 0.17677669529663687f
#define WSTRIDE 136   // shorts: 68 dwords %32 = 4 -> 2-way max (free)
#define W2STRIDE 68   // shorts: 34 dwords %32 = 2 -> all 16 rows distinct banks

typedef short short8 __attribute__((ext_vector_type(8)));
typedef float f32x4 __attribute__((ext_vector_type(4)));

__device__ __forceinline__ short f2bf(float f) {
    union { float f; unsigned u; } c; c.f = f;
    unsigned r = (c.u + 0x7fff + ((c.u >> 16) & 1)) >> 16;
    return (short)r;
}
__device__ __forceinline__ unsigned pack2bf(float a, float b) {
    return (unsigned)(unsigned short)f2bf(a) | ((unsigned)(unsigned short)f2bf(b) << 16);
}
__device__ __forceinline__ float gelu_fast(float x) {
    float x3 = x * x * x;
    float y = 0.7978845608f * (x + 0.044715f * x3);
    float e = __expf(2.f * y);
    float t = 1.f - 2.f / (e + 1.f);
    return 0.5f * x * (1.f + t);
}
#define LDS_FENCE() asm volatile("s_waitcnt lgkmcnt(0)" ::: "memory")

// ---------------------------------------------------------------------------
__global__ void conv_t(const float* __restrict__ in, short* __restrict__ out,
                       int K, int N) {
    int idx = blockIdx.x * 256 + threadIdx.x;
    if (idx >= K * N) return;
    int k = idx / N, n = idx % N;
    out[(size_t)n * K + k] = f2bf(in[idx]);
}

// ---------------------------------------------------------------------------
__global__ void build_table(const float* __restrict__ rpb, float* __restrict__ table) {
    int idx = blockIdx.x * 256 + threadIdx.x;
    if (idx >= 16 * 4096) return;
    int cell = idx & 4095, ch = idx >> 12;
    int cls = ch >> 2, hd = ch & 3;
    int row = cell >> 6, col = cell & 63;
    float v;
    if (row >= Nn || col >= Nn) v = -1e30f;
    else {
        int i1 = row / 7, j1 = row % 7, i2 = col / 7, j2 = col % 7;
        float bias = rpb[((i1 - i2 + 6) * 13 + (j1 - j2 + 6)) * HEAD + hd];
        int bh = cls >> 1, bw = cls & 1;
        int rn = bh ? (i1 < 4 ? 1 : 2) : 0;
        int cn = bw ? (j1 < 4 ? 1 : 2) : 0;
        int rm = bh ? (i2 < 4 ? 1 : 2) : 0;
        int cm = bw ? (j2 < 4 ? 1 : 2) : 0;
        v = bias + (((rn * 3 + cn) != (rm * 3 + cm)) ? -100.f : 0.f);
    }
    table[idx] = v;
}

// ---------------------------------------------------------------------------
__global__ __launch_bounds__(256) void ln1_gather(const float* __restrict__ x,
                                                  const float* __restrict__ g,
                                                  const float* __restrict__ b,
                                                  short* __restrict__ h) {
    int wave = threadIdx.x >> 6, lane = threadIdx.x & 63;
    int t = blockIdx.x * 4 + wave;
    int bimg = t / (NWw * Nn);
    int wrow = t % (NWw * Nn);
    int wi = wrow / Nn, n = wrow % Nn;
    int wh = wi >> 3, ww = wi & 7;
    int i = n / 7, j = n % 7;
    int sr = (wh * 7 + i + SHIFT) % Hh;
    int scol = (ww * 7 + j + SHIFT) % Ww;
    const float* xr = x + ((size_t)bimg * (Hh * Ww) + sr * Ww + scol) * Cc;
    float2 v = ((const float2*)xr)[lane];
    float s = v.x + v.y;
    #pragma unroll
    for (int m = 32; m; m >>= 1) s += __shfl_xor(s, m, 64);
    float mean = s * (1.f / 128.f);
    float dx = v.x - mean, dy = v.y - mean;
    float vs = dx * dx + dy * dy;
    #pragma unroll
    for (int m = 32; m; m >>= 1) vs += __shfl_xor(vs, m, 64);
    float inv = rsqrtf(vs * (1.f / 128.f) + 1e-5f);
    float2 gg = ((const float2*)g)[lane];
    float2 bb = ((const float2*)b)[lane];
    ((unsigned*)(h + (size_t)t * Cc))[lane] =
        pack2bf(dx * inv * gg.x + bb.x, dy * inv * gg.y + bb.y);
}

// ---------------------------------------------------------------------------
// QKV GEMM: 64 tokens/block (16/wave). W chunk staged in LDS.
// ---------------------------------------------------------------------------
__global__ __launch_bounds__(256, 3) void qkv_mfma(const short* __restrict__ h,
                                                   const short* __restrict__ wt,
                                                   const float* __restrict__ bias,
                                                   short* __restrict__ qkv) {
    __shared__ short Wc[128 * WSTRIDE];
    int tid = threadIdx.x;
    int wave = tid >> 6, lane = tid & 63;
    int row16 = lane & 15, quad = lane >> 4;
    size_t t0 = (size_t)blockIdx.x * 64 + wave * 16;
    short8 afr[4];
    #pragma unroll
    for (int k = 0; k < 4; ++k)
        afr[k] = *(const short8*)(h + (t0 + row16) * Cc + k * 32 + quad * 8);
    int srow = tid >> 4, skof = (tid & 15) * 8;
    for (int ch = 0; ch < 3; ++ch) {
        __syncthreads();
        #pragma unroll
        for (int i = 0; i < 8; ++i) {
            int r = srow + i * 16;
            short8 w = *(const short8*)(wt + (size_t)(ch * 128 + r) * Cc + skof);
            *(short8*)(Wc + r * WSTRIDE + skof) = w;
        }
        __syncthreads();
        f32x4 acc[8];
        #pragma unroll
        for (int n = 0; n < 8; ++n) acc[n] = (f32x4)(0.f);
        #pragma unroll
        for (int k = 0; k < 4; ++k) {
            #pragma unroll
            for (int n = 0; n < 8; ++n) {
                short8 bfr = *(const short8*)(Wc + (n * 16 + row16) * WSTRIDE + k * 32 + quad * 8);
                acc[n] = __builtin_amdgcn_mfma_f32_16x16x32_bf16(afr[k], bfr, acc[n], 0, 0, 0);
            }
        }
        #pragma unroll
        for (int n = 0; n < 8; ++n) {
            int col = ch * 128 + n * 16 + row16;
            float bv = bias[col];
            #pragma unroll
            for (int r = 0; r < 4; ++r) {
                float val = acc[n][r] + bv;
                if (ch == 0) val *= SCALEF;
                qkv[(t0 + quad * 4 + r) * 384 + col] = f2bf(val);
            }
        }
    }
}

// ---------------------------------------------------------------------------
// MFMA attention: one wave per (window, head); 2 waves/block.
// ---------------------------------------------------------------------------
__global__ __launch_bounds__(128, 3) void attn_mfma(const short* __restrict__ qkv,
                                                    const float* __restrict__ table,
                                                    short* __restrict__ o) {
    __shared__ short Pbuf[2][64 * 72];
    __shared__ short Vbuf[2][32 * 72];
    int wave = threadIdx.x >> 6, lane = threadIdx.x & 63;
    int row16 = lane & 15, quad = lane >> 4;
    int unit = blockIdx.x * 2 + wave;
    int bw = unit >> 2, hd = unit & 3;
    int widx = bw & 63, wh = widx >> 3, ww = widx & 7;
    int cls = ((wh == 7) ? 2 : 0) | ((ww == 7) ? 1 : 0);
    const float* tb = table + ((size_t)(cls * 4 + hd)) * 4096;
    short* P = &Pbuf[wave][0];
    short* vt = &Vbuf[wave][0];
    const short* base = qkv + (size_t)bw * Nn * 384 + hd * HD;

    {
        int t = lane;
        if (t < Nn) {
            const short* vrow = base + (size_t)t * 384 + 256;
            #pragma unroll
            for (int d = 0; d < HD; d += 2) {
                unsigned pr = *(const unsigned*)(vrow + d);
                vt[d * 72 + t] = (short)(pr & 0xffff);
                vt[(d + 1) * 72 + t] = (short)(pr >> 16);
            }
        } else {
            #pragma unroll
            for (int d = 0; d < HD; ++d) vt[d * 72 + t] = 0;
        }
    }

    short8 qa[4], kb[4];
    #pragma unroll
    for (int mt = 0; mt < 4; ++mt) {
        int r = mt * 16 + row16;
        if (r < Nn) {
            qa[mt] = *(const short8*)(base + (size_t)r * 384 + quad * 8);
            kb[mt] = *(const short8*)(base + (size_t)r * 384 + 128 + quad * 8);
        } else {
            qa[mt] = (short8)(short)0;
            kb[mt] = (short8)(short)0;
        }
    }
    f32x4 s[4][4];
    #pragma unroll
    for (int mt = 0; mt < 4; ++mt)
        #pragma unroll
        for (int nt = 0; nt < 4; ++nt)
            s[mt][nt] = __builtin_amdgcn_mfma_f32_16x16x32_bf16(qa[mt], kb[nt], (f32x4)(0.f), 0, 0, 0);

    #pragma unroll
    for (int mt = 0; mt < 4; ++mt) {
        #pragma unroll
        for (int r = 0; r < 4; ++r) {
            int row = mt * 16 + quad * 4 + r;
            float mx = -1e30f;
            #pragma unroll
            for (int nt = 0; nt < 4; ++nt) {
                s[mt][nt][r] += tb[row * 64 + nt * 16 + row16];
                mx = fmaxf(mx, s[mt][nt][r]);
            }
            #pragma unroll
            for (int m = 1; m < 16; m <<= 1) mx = fmaxf(mx, __shfl_xor(mx, m, 64));
            float sm = 0.f;
            #pragma unroll
            for (int nt = 0; nt < 4; ++nt) {
                float e = __expf(s[mt][nt][r] - mx);
                s[mt][nt][r] = e;
                sm += e;
            }
            #pragma unroll
            for (int m = 1; m < 16; m <<= 1) sm += __shfl_xor(sm, m, 64);
            float inv = 1.f / sm;
            #pragma unroll
            for (int nt = 0; nt < 4; ++nt)
                P[row * 72 + nt * 16 + row16] = f2bf(s[mt][nt][r] * inv);
        }
    }
    LDS_FENCE();

    f32x4 oacc[4][2];
    #pragma unroll
    for (int mt = 0; mt < 4; ++mt)
        #pragma unroll
        for (int nt = 0; nt < 2; ++nt) oacc[mt][nt] = (f32x4)(0.f);
    #pragma unroll
    for (int kt = 0; kt < 2; ++kt) {
        short8 pa[4], vb[2];
        #pragma unroll
        for (int mt = 0; mt < 4; ++mt)
            pa[mt] = *(const short8*)(P + (mt * 16 + row16) * 72 + kt * 32 + quad * 8);
        #pragma unroll
        for (int nt = 0; nt < 2; ++nt)
            vb[nt] = *(const short8*)(vt + (nt * 16 + row16) * 72 + kt * 32 + quad * 8);
        #pragma unroll
        for (int mt = 0; mt < 4; ++mt)
            #pragma unroll
            for (int nt = 0; nt < 2; ++nt)
                oacc[mt][nt] = __builtin_amdgcn_mfma_f32_16x16x32_bf16(pa[mt], vb[nt], oacc[mt][nt], 0, 0, 0);
    }
    #pragma unroll
    for (int mt = 0; mt < 4; ++mt)
        #pragma unroll
        for (int nt = 0; nt < 2; ++nt)
            #pragma unroll
            for (int r = 0; r < 4; ++r) {
                int row = mt * 16 + quad * 4 + r;
                if (row < Nn)
                    o[((size_t)bw * Nn + row) * Cc + hd * HD + nt * 16 + row16] = f2bf(oacc[mt][nt][r]);
            }
}

// ---------------------------------------------------------------------------
// Proj: 64 tokens/block (16/wave). W staged once; scatter + LN2.
// ---------------------------------------------------------------------------
__global__ __launch_bounds__(256, 3) void proj_ln2(const short* __restrict__ o,
                                                   const short* __restrict__ wt,
                                                   const float* __restrict__ pb,
                                                   const float* __restrict__ x,
                                                   const float* __restrict__ g2,
                                                   const float* __restrict__ b2,
                                                   float* __restrict__ x1,
                                                   short* __restrict__ m) {
    __shared__ short Wc[128 * WSTRIDE];
    __shared__ int dest[64];
    int tid = threadIdx.x;
    int wave = tid >> 6, lane = tid & 63;
    int row16 = lane & 15, quad = lane >> 4;
    int s0 = blockIdx.x * 64;
    {
        int srow = tid >> 4, skof = (tid & 15) * 8;
        #pragma unroll
        for (int i = 0; i < 8; ++i) {
            int r = srow + i * 16;
            short8 w = *(const short8*)(wt + (size_t)r * Cc + skof);
            *(short8*)(Wc + r * WSTRIDE + skof) = w;
        }
    }
    if (tid < 64) {
        int st = s0 + tid;
        int bimg = st / (NWw * Nn);
        int rem = st % (NWw * Nn);
        int wi = rem / Nn, n = rem % Nn;
        int wh = wi >> 3, ww = wi & 7;
        int i = n / 7, j = n % 7;
        int dr = (wh * 7 + i + SHIFT) % Hh;
        int dc = (ww * 7 + j + SHIFT) % Ww;
        dest[tid] = bimg * (Hh * Ww) + dr * Ww + dc;
    }
    __syncthreads();
    int r0w = wave * 16;
    short8 afr[4];
    #pragma unroll
    for (int k = 0; k < 4; ++k)
        afr[k] = *(const short8*)(o + ((size_t)s0 + r0w + row16) * Cc + k * 32 + quad * 8);
    f32x4 acc[8];
    #pragma unroll
    for (int n = 0; n < 8; ++n) acc[n] = (f32x4)(0.f);
    #pragma unroll
    for (int k = 0; k < 4; ++k) {
        #pragma unroll
        for (int n = 0; n < 8; ++n) {
            short8 bfr = *(const short8*)(Wc + (n * 16 + row16) * WSTRIDE + k * 32 + quad * 8);
            acc[n] = __builtin_amdgcn_mfma_f32_16x16x32_bf16(afr[k], bfr, acc[n], 0, 0, 0);
        }
    }
    float gv[8], bv[8], pbv[8];
    #pragma unroll
    for (int n = 0; n < 8; ++n) {
        int col = n * 16 + row16;
        gv[n] = g2[col]; bv[n] = b2[col]; pbv[n] = pb[col];
    }
    #pragma unroll
    for (int r = 0; r < 4; ++r) {
        int di = dest[r0w + quad * 4 + r];
        #pragma unroll
        for (int n = 0; n < 8; ++n)
            acc[n][r] += x[(size_t)di * Cc + n * 16 + row16] + pbv[n];
        float sum = 0.f;
        #pragma unroll
        for (int n = 0; n < 8; ++n) sum += acc[n][r];
        #pragma unroll
        for (int mk = 1; mk < 16; mk <<= 1) sum += __shfl_xor(sum, mk, 64);
        float mean = sum * (1.f / 128.f);
        float var = 0.f;
        #pragma unroll
        for (int n = 0; n < 8; ++n) {
            float d = acc[n][r] - mean;
            var += d * d;
        }
        #pragma unroll
        for (int mk = 1; mk < 16; mk <<= 1) var += __shfl_xor(var, mk, 64);
        float inv = rsqrtf(var * (1.f / 128.f) + 1e-5f);
        #pragma unroll
        for (int n = 0; n < 8; ++n) {
            size_t idx = (size_t)di * Cc + n * 16 + row16;
            float v = acc[n][r];
            x1[idx] = v;
            m[idx] = f2bf((v - mean) * inv * gv[n] + bv[n]);
        }
    }
}

// ---------------------------------------------------------------------------
// Fused MLP: 64 tokens/block (16/wave). Per 64-hid chunk, BOTH the W1 chunk
// and the W2 k-slice are staged into LDS — zero global loads in the compute
// path. LDS = 17.4+17.4+9.2 = 44 KB -> 3 blocks/CU; LB(256,3) -> ~170 VGPR.
// ---------------------------------------------------------------------------
#define HSTRIDE 72
__global__ __launch_bounds__(256, 3) void mlp_mfma(const short* __restrict__ m,
                                                   const short* __restrict__ w1t,
                                                   const float* __restrict__ b1,
                                                   const short* __restrict__ w2t,
                                                   const float* __restrict__ b2,
                                                   const float* __restrict__ x1,
                                                   float* __restrict__ out) {
    __shared__ short W1c[64 * WSTRIDE];
    __shared__ short W2c[128 * W2STRIDE];
    __shared__ short Hs[4][16 * HSTRIDE];
    int tid = threadIdx.x;
    int wave = tid >> 6, lane = tid & 63;
    int row16 = lane & 15, quad = lane >> 4;
    size_t t0 = (size_t)blockIdx.x * 64 + wave * 16;
    short* Ht = &Hs[wave][0];
    short8 bfr[4];
    #pragma unroll
    for (int k = 0; k < 4; ++k)
        bfr[k] = *(const short8*)(m + (t0 + row16) * Cc + k * 32 + quad * 8);
    f32x4 acc2[8];
    #pragma unroll
    for (int n = 0; n < 8; ++n) acc2[n] = (f32x4)(0.f);
    for (int ch = 0; ch < 8; ++ch) {
        __syncthreads();
        // stage W1 chunk: 64 rows x 128 shorts = 1024 b128 segs, 4/thread
        #pragma unroll
        for (int i = 0; i < 4; ++i) {
            int s = tid + i * 256;
            int r = s >> 4, c = (s & 15) * 8;
            short8 w = *(const short8*)(w1t + (size_t)(ch * 64 + r) * Cc + c);
            *(short8*)(W1c + r * WSTRIDE + c) = w;
        }
        // stage W2 k-slice: 128 rows x 64 shorts = 1024 b128 segs, 4/thread
        #pragma unroll
        for (int i = 0; i < 4; ++i) {
            int s = tid + i * 256;
            int n = s >> 3, c = (s & 7) * 8;
            short8 w = *(const short8*)(w2t + (size_t)n * HID + ch * 64 + c);
            *(short8*)(W2c + n * W2STRIDE + c) = w;
        }
        __syncthreads();
        // FC1: C[m=hid(64)][n=tok(16)]
        f32x4 acc1[4];
        #pragma unroll
        for (int mt = 0; mt < 4; ++mt) acc1[mt] = (f32x4)(0.f);
        #pragma unroll
        for (int k = 0; k < 4; ++k) {
            #pragma unroll
            for (int mt = 0; mt < 4; ++mt) {
                short8 a = *(const short8*)(W1c + (mt * 16 + row16) * WSTRIDE + k * 32 + quad * 8);
                acc1[mt] = __builtin_amdgcn_mfma_f32_16x16x32_bf16(a, bfr[k], acc1[mt], 0, 0, 0);
            }
        }
        // GELU -> per-wave H[tok(16)][hid(64)]
        #pragma unroll
        for (int mt = 0; mt < 4; ++mt) {
            int hidb = ch * 64 + mt * 16 + quad * 4;
            f32x4 b1v = *(const f32x4*)(b1 + hidb);
            float h0 = gelu_fast(acc1[mt][0] + b1v[0]);
            float h1 = gelu_fast(acc1[mt][1] + b1v[1]);
            float h2 = gelu_fast(acc1[mt][2] + b1v[2]);
            float h3 = gelu_fast(acc1[mt][3] + b1v[3]);
            uint2 pk;
            pk.x = pack2bf(h0, h1);
            pk.y = pack2bf(h2, h3);
            *(uint2*)(Ht + row16 * HSTRIDE + mt * 16 + quad * 4) = pk;
        }
        LDS_FENCE();
        // FC2 partial over k = [ch*64, ch*64+64), all operands from LDS
        #pragma unroll
        for (int kk = 0; kk < 2; ++kk) {
            short8 ha = *(const short8*)(Ht + row16 * HSTRIDE + kk * 32 + quad * 8);
            #pragma unroll
            for (int n = 0; n < 8; ++n) {
                short8 wb = *(const short8*)(W2c + (n * 16 + row16) * W2STRIDE + kk * 32 + quad * 8);
                acc2[n] = __builtin_amdgcn_mfma_f32_16x16x32_bf16(ha, wb, acc2[n], 0, 0, 0);
            }
        }
    }
    #pragma unroll
    for (int n = 0; n < 8; ++n) {
        int col = n * 16 + row16;
        float bb = b2[col];
        #pragma unroll
        for (int r = 0; r < 4; ++r) {
            size_t idx = (t0 + quad * 4 + r) * Cc + col;
            out[idx] = x1[idx] + bb + acc2[n][r];
        }
    }
}

// ---------------------------------------------------------------------------
extern "C" void kernel_launch(void* const* d_in, const int* in_sizes, int n_in,
                              void* d_out, int out_size, void* d_ws, size_t ws_size,
                              hipStream_t stream) {
    const float* x     = (const float*)d_in[0];
    const float* n1g   = (const float*)d_in[1];
    const float* n1b   = (const float*)d_in[2];
    const float* qkvw  = (const float*)d_in[3];
    const float* qkvb  = (const float*)d_in[4];
    const float* projw = (const float*)d_in[5];
    const float* projb = (const float*)d_in[6];
    const float* rpb   = (const float*)d_in[7];
    const float* n2g   = (const float*)d_in[8];
    const float* n2b   = (const float*)d_in[9];
    const float* fc1w  = (const float*)d_in[10];
    const float* fc1b  = (const float*)d_in[11];
    const float* fc2w  = (const float*)d_in[12];
    const float* fc2b  = (const float*)d_in[13];
    float* out = (float*)d_out;

    char* ws = (char*)d_ws;
    short* qkv   = (short*)ws;
    float* x1    = (float*)(ws + 77070336);
    float* table = x1;  // dead until proj_ln2 writes x1 (attn reads it first)
    short* h     = (short*)(ws + 77070336 + 51380224);
    short* m     = h;
    short* o     = (short*)(ws + 77070336 + 51380224 + 25690112);
    short* qkvwT = (short*)(ws + 77070336 + 51380224 + 2 * 25690112);
    short* projwT= qkvwT + 384 * 128;
    short* fc1wT = projwT + 128 * 128;
    short* fc2wT = fc1wT + 512 * 128;

    conv_t<<<(128 * 384 + 255) / 256, 256, 0, stream>>>(qkvw, qkvwT, 128, 384);
    conv_t<<<(128 * 128 + 255) / 256, 256, 0, stream>>>(projw, projwT, 128, 128);
    conv_t<<<(128 * 512 + 255) / 256, 256, 0, stream>>>(fc1w, fc1wT, 128, 512);
    conv_t<<<(512 * 128 + 255) / 256, 256, 0, stream>>>(fc2w, fc2wT, 512, 128);
    build_table<<<256, 256, 0, stream>>>(rpb, table);

    ln1_gather<<<TOK / 4, 256, 0, stream>>>(x, n1g, n1b, h);
    qkv_mfma<<<TOK / 64, 256, 0, stream>>>(h, qkvwT, qkvb, qkv);
    attn_mfma<<<(TOK / Nn) * HEAD / 2, 128, 0, stream>>>(qkv, table, o);
    proj_ln2<<<TOK / 64, 256, 0, stream>>>(o, projwT, projb, x, n2g, n2b, x1, m);
    mlp_mfma<<<TOK / 64, 256, 0, stream>>>(m, fc1wT, fc1b, fc2wT, fc2b, x1, out);
}